// Round 2
// baseline (46296.008 us; speedup 1.0000x reference)
//
#include <hip/hip_runtime.h>
#include <stdint.h>
#include <stddef.h>

// PowerLawLayer RNN, MI355X persistent-kernel, R2.
//
// R1 failure: __launch_bounds__(1024) => 128-VGPR cap; compiler allocated 64
// and spilled the 144-float/thread weight arrays => 90 GB/dispatch scratch
// traffic (FETCH_SIZE), VALUBusy 5.3%, 39 ms.
//
// R2: 512-thread wgs, 1 wg/CU => 2 waves/SIMD => 256-VGPR cap; 144 weight
// floats/thread now genuinely register-resident.
//   wg = (32 j's) x (full k=768) x (4 batches). 256 wgs = 16 slices x 16
//   batch groups. Peers = 16 wgs per batch group, same XCD via bid swizzle.
//   lane l: jj = l&31 (hidden unit), half = l>>5; kc = 2*wave + half in
//   [0,16): each kc owns 32 h-k + 16 x-k (same k-partition as R1).
//   Per lane per step: 3 gates x 48 k x 4 batches = 576 FMAs;
//   per SIMD: 2 waves x 576 x 2 cyc = 2304 cyc = the fp32 FMA floor.
//   Halves combined via shfl_xor(32); partials in LDS stride-33 (2-way max).
//
// Workspace: hbuf[2][64][512] f32 ping-pong + ctr[32] = 262,272 B.

#define Hh   512
#define Tt   1024
#define Bb   64
#define II   256
#define EPSc 0.001f
#define PV   0.2f
#define NPEER 16

__global__ __launch_bounds__(1024) void plr_init(float* hbuf, unsigned* ctr) {
  int idx = blockIdx.x * blockDim.x + threadIdx.x;
  if (idx < Bb * Hh) hbuf[idx] = 0.0f;        // h(0) = 0 in buffer 0
  if (idx < 32) ctr[idx] = 0u;                // barrier counters
}

__global__ __launch_bounds__(512) void plr_main(
    const float* __restrict__ x,    // [B, T, I]
    const float* __restrict__ Wih,  // [3H, I]
    const float* __restrict__ Whh,  // [3H, H]
    const float* __restrict__ bias, // [3H]
    float* __restrict__ out,        // [B,T,H] ++ h_f ++ c_f ++ k_f
    float* hbuf,                    // [2][B][H]
    unsigned* ctr)                  // [32]
{
  __shared__ float h_tile[4 * Hh];   // [bl][k]  8 KB
  __shared__ float x_tile[4 * II];   // [bl][k]  4 KB
  __shared__ float part2[3168];      // ((gi*4+bl)*8 + w)*33 + jj  12.4 KB

  const int tid  = threadIdx.x;
  const int w    = tid >> 6;         // wave 0..7
  const int l    = tid & 63;
  const int jj   = l & 31;           // hidden offset within slice
  const int half = l >> 5;
  const int kc   = (w << 1) | half;  // k-chunk 0..15
  const int bid  = blockIdx.x;
  // peers (same batch group g) share bid&7 => same XCD under round-robin
  const int xcd = bid & 7, rr = bid >> 3;
  const int g  = (xcd << 1) | (rr & 1);  // batch group 0..15
  const int s  = rr >> 1;                // hidden slice 0..15
  const int j0 = s * 32;
  const int b0 = g * 4;

  // ---- one-time: weights into registers (144 floats/thread) -----------
  float whh[3][32];
  float wih[3][16];
#pragma unroll
  for (int gi = 0; gi < 3; ++gi) {
    const int row = gi * Hh + j0 + jj;
    const float4* ph = (const float4*)(Whh + (size_t)row * Hh + kc * 32);
#pragma unroll
    for (int i = 0; i < 8; ++i) {
      float4 v = ph[i];
      whh[gi][4*i+0] = v.x; whh[gi][4*i+1] = v.y;
      whh[gi][4*i+2] = v.z; whh[gi][4*i+3] = v.w;
    }
    const float4* pi = (const float4*)(Wih + (size_t)row * II + kc * 16);
#pragma unroll
    for (int i = 0; i < 4; ++i) {
      float4 v = pi[i];
      wih[gi][4*i+0] = v.x; wih[gi][4*i+1] = v.y;
      wih[gi][4*i+2] = v.z; wih[gi][4*i+3] = v.w;
    }
  }

  // ---- updater state (threads 0..127: bl = tid>>5, j = j0 + (tid&31)) --
  float c_st = 0.0f, k_st = -1.0f;
  float bia0 = 0.f, bia1 = 0.f, bia2 = 0.f;
  if (tid < 128) {
    const int jr = tid & 31;
    bia0 = bias[0 * Hh + j0 + jr];
    bia1 = bias[1 * Hh + j0 + jr];
    bia2 = bias[2 * Hh + j0 + jr];
  }

  bool broken = false;  // bounded-spin escape (never taken when co-resident)

  for (int t = 0; t < Tt; ++t) {
    // ---- stage h(t) (LLC-coherent) and x_t into LDS --------------------
    {
      const int bl = tid >> 7;          // 0..3
      const int kk = tid & 127;
      const float* hb = hbuf + (size_t)(t & 1) * Bb * Hh +
                        (size_t)(b0 + bl) * Hh + kk * 4;
      float4 hv;
      hv.x = __hip_atomic_load(hb + 0, __ATOMIC_RELAXED, __HIP_MEMORY_SCOPE_AGENT);
      hv.y = __hip_atomic_load(hb + 1, __ATOMIC_RELAXED, __HIP_MEMORY_SCOPE_AGENT);
      hv.z = __hip_atomic_load(hb + 2, __ATOMIC_RELAXED, __HIP_MEMORY_SCOPE_AGENT);
      hv.w = __hip_atomic_load(hb + 3, __ATOMIC_RELAXED, __HIP_MEMORY_SCOPE_AGENT);
      *(float4*)(h_tile + bl * Hh + kk * 4) = hv;
      const float* xb = x + ((size_t)(b0 + bl) * Tt + t) * II + kk * 2;
      float2 xv = *(const float2*)xb;
      *(float2*)(x_tile + bl * II + kk * 2) = xv;
    }
    __syncthreads();

    // ---- gemv: 576 FMA/thread, broadcast LDS reads ---------------------
    float acc[3][4];
#pragma unroll
    for (int bl = 0; bl < 4; ++bl) {
      const float4* h4 = (const float4*)(h_tile + bl * Hh) + kc * 8;
      const float4* x4 = (const float4*)(x_tile + bl * II) + kc * 4;
      float a0 = 0.f, a1 = 0.f, a2 = 0.f;
#pragma unroll
      for (int i = 0; i < 8; ++i) {
        float4 hv = h4[i];
        a0 = fmaf(whh[0][4*i+0], hv.x, a0); a0 = fmaf(whh[0][4*i+1], hv.y, a0);
        a0 = fmaf(whh[0][4*i+2], hv.z, a0); a0 = fmaf(whh[0][4*i+3], hv.w, a0);
        a1 = fmaf(whh[1][4*i+0], hv.x, a1); a1 = fmaf(whh[1][4*i+1], hv.y, a1);
        a1 = fmaf(whh[1][4*i+2], hv.z, a1); a1 = fmaf(whh[1][4*i+3], hv.w, a1);
        a2 = fmaf(whh[2][4*i+0], hv.x, a2); a2 = fmaf(whh[2][4*i+1], hv.y, a2);
        a2 = fmaf(whh[2][4*i+2], hv.z, a2); a2 = fmaf(whh[2][4*i+3], hv.w, a2);
      }
#pragma unroll
      for (int i = 0; i < 4; ++i) {
        float4 xv = x4[i];
        a0 = fmaf(wih[0][4*i+0], xv.x, a0); a0 = fmaf(wih[0][4*i+1], xv.y, a0);
        a0 = fmaf(wih[0][4*i+2], xv.z, a0); a0 = fmaf(wih[0][4*i+3], xv.w, a0);
        a1 = fmaf(wih[1][4*i+0], xv.x, a1); a1 = fmaf(wih[1][4*i+1], xv.y, a1);
        a1 = fmaf(wih[1][4*i+2], xv.z, a1); a1 = fmaf(wih[1][4*i+3], xv.w, a1);
        a2 = fmaf(wih[2][4*i+0], xv.x, a2); a2 = fmaf(wih[2][4*i+1], xv.y, a2);
        a2 = fmaf(wih[2][4*i+2], xv.z, a2); a2 = fmaf(wih[2][4*i+3], xv.w, a2);
      }
      acc[0][bl] = a0; acc[1][bl] = a1; acc[2][bl] = a2;
    }
    // combine the two k-halves in-register, then one conflict-free store
#pragma unroll
    for (int gi = 0; gi < 3; ++gi)
#pragma unroll
      for (int bl = 0; bl < 4; ++bl) {
        float v = acc[gi][bl] + __shfl_xor(acc[gi][bl], 32, 64);
        if (half == 0) part2[((gi * 4 + bl) * 8 + w) * 33 + jj] = v;
      }
    __syncthreads();

    // ---- reduce + elementwise + store (threads 0..127) -----------------
    if (tid < 128) {
      const int jr = tid & 31, br = tid >> 5;
      float s0 = bia0, s1 = bia1, s2 = bia2;
#pragma unroll
      for (int ww = 0; ww < 8; ++ww) {
        s0 += part2[((0 * 4 + br) * 8 + ww) * 33 + jr];
        s1 += part2[((1 * 4 + br) * 8 + ww) * 33 + jr];
        s2 += part2[((2 * 4 + br) * 8 + ww) * 33 + jr];
      }
      const float tf = (float)t;
      const float r  = 1.0f / (1.0f + __expf(-s0));
      const float o  = 1.0f / (1.0f + __expf(-s1));
      const float gg = 1.0f - 2.0f / (1.0f + __expf(2.0f * s2));
      const float kn = r * (tf - EPSc) + (1.0f - r) * k_st;
      const float d  = tf - kn;
      const float f  = __expf(PV * __logf((d + EPSc) / (d + 1.0f)));
      const float cn = f * c_st + (1.0f - f) * gg;
      const float hn = o * (1.0f - 2.0f / (1.0f + __expf(2.0f * cn)));
      c_st = cn; k_st = kn;
      const int b = b0 + br, j = j0 + jr;
      out[((size_t)b * Tt + t) * Hh + j] = hn;
      __hip_atomic_store(
          hbuf + (size_t)((t + 1) & 1) * Bb * Hh + (size_t)b * Hh + j, hn,
          __ATOMIC_RELAXED, __HIP_MEMORY_SCOPE_AGENT);
      if (t == Tt - 1) {
        const size_t base = (size_t)Bb * Tt * Hh;
        out[base + 0 * Bb * Hh + (size_t)b * Hh + j] = hn;  // h_f
        out[base + 1 * Bb * Hh + (size_t)b * Hh + j] = cn;  // c_f
        out[base + 2 * Bb * Hh + (size_t)b * Hh + j] = kn;  // k_f
      }
    }

    // ---- 16-peer barrier (skip after last step) ------------------------
    if (t < Tt - 1) {
      __syncthreads();  // drains updater global stores before the signal
      if (tid == 0) {
        __hip_atomic_fetch_add(ctr + g, 1u, __ATOMIC_RELEASE,
                               __HIP_MEMORY_SCOPE_AGENT);
        if (!broken) {
          const unsigned target = (unsigned)NPEER * (unsigned)(t + 1);
          int it = 0;
          while (__hip_atomic_load(ctr + g, __ATOMIC_ACQUIRE,
                                   __HIP_MEMORY_SCOPE_AGENT) < target) {
            __builtin_amdgcn_s_sleep(2);
            if (++it > (1 << 22)) { broken = true; break; }
          }
        }
      }
      __syncthreads();  // all threads see acquire via tid0 + barrier
    }
  }
}

extern "C" void kernel_launch(void* const* d_in, const int* in_sizes, int n_in,
                              void* d_out, int out_size, void* d_ws, size_t ws_size,
                              hipStream_t stream) {
  const float* x    = (const float*)d_in[0];
  const float* Wih  = (const float*)d_in[1];
  const float* Whh  = (const float*)d_in[2];
  const float* bias = (const float*)d_in[3];
  float* out = (float*)d_out;

  float*    hbuf = (float*)d_ws;                                  // 2*64*512 f32
  unsigned* ctr  = (unsigned*)((char*)d_ws + 2 * Bb * Hh * sizeof(float));

  plr_init<<<32, 1024, 0, stream>>>(hbuf, ctr);
  plr_main<<<256, 512, 0, stream>>>(x, Wih, Whh, bias, out, hbuf, ctr);
}

// Round 3
// 43565.906 us; speedup vs baseline: 1.0627x; 1.0627x over previous
//
#include <hip/hip_runtime.h>
#include <stdint.h>
#include <stddef.h>

// PowerLawLayer RNN, MI355X persistent-kernel, R3.
//
// R1: __launch_bounds__(1024) => 128-VGPR cap => weights spilled, 39 ms.
// R2: 512-thr wgs but no waves-per-eu pin => allocator chose 128 VGPR
//     (4 waves/EU heuristic), still spilled half the weights: FETCH 27 GB,
//     WRITE 855 MB (spill stores), VALUBusy 4.8%, 44 ms.
// R3: amdgpu_waves_per_eu(2,2) pins 2 waves/SIMD => 256-VGPR budget, the
//     144 weight floats/thread (+ ~56 temps) fit with zero spill.
//
//   wg = (32 j's) x (full k=768) x (4 batches). 256 wgs = 16 slices x 16
//   batch groups. Peers = 16 wgs per batch group, same XCD via bid swizzle.
//   lane l: jj = l&31 (hidden unit), half = l>>5; kc = 2*wave + half in
//   [0,16): each kc owns 32 h-k + 16 x-k.
//   Per lane per step: 3 gates x 48 k x 4 batches = 576 FMAs;
//   per SIMD: 2 waves x 576 x 2 cyc = 2304 cyc = the fp32 FMA floor
//   (~0.96 us/step, ~1 ms total).
//   Halves combined via shfl_xor(32); partials in LDS stride-33 (2-way max).
//
// Workspace: hbuf[2][64][512] f32 ping-pong + ctr[32] = 262,272 B.

#define Hh   512
#define Tt   1024
#define Bb   64
#define II   256
#define EPSc 0.001f
#define PV   0.2f
#define NPEER 16

__global__ __launch_bounds__(1024) void plr_init(float* hbuf, unsigned* ctr) {
  int idx = blockIdx.x * blockDim.x + threadIdx.x;
  if (idx < Bb * Hh) hbuf[idx] = 0.0f;        // h(0) = 0 in buffer 0
  if (idx < 32) ctr[idx] = 0u;                // barrier counters
}

__global__ __launch_bounds__(512)
__attribute__((amdgpu_waves_per_eu(2, 2)))    // pin 2 waves/SIMD: 256-VGPR cap,
void plr_main(                                 // forbid 128-VGPR repacking
    const float* __restrict__ x,    // [B, T, I]
    const float* __restrict__ Wih,  // [3H, I]
    const float* __restrict__ Whh,  // [3H, H]
    const float* __restrict__ bias, // [3H]
    float* __restrict__ out,        // [B,T,H] ++ h_f ++ c_f ++ k_f
    float* hbuf,                    // [2][B][H]
    unsigned* ctr)                  // [32]
{
  __shared__ float h_tile[4 * Hh];   // [bl][k]  8 KB
  __shared__ float x_tile[4 * II];   // [bl][k]  4 KB
  __shared__ float part2[3168];      // ((gi*4+bl)*8 + w)*33 + jj  12.4 KB

  const int tid  = threadIdx.x;
  const int w    = tid >> 6;         // wave 0..7
  const int l    = tid & 63;
  const int jj   = l & 31;           // hidden offset within slice
  const int half = l >> 5;
  const int kc   = (w << 1) | half;  // k-chunk 0..15
  const int bid  = blockIdx.x;
  // peers (same batch group g) share bid&7 => same XCD under round-robin
  const int xcd = bid & 7, rr = bid >> 3;
  const int g  = (xcd << 1) | (rr & 1);  // batch group 0..15
  const int s  = rr >> 1;                // hidden slice 0..15
  const int j0 = s * 32;
  const int b0 = g * 4;

  // ---- one-time: weights into registers (144 floats/thread) -----------
  float whh[3][32];
  float wih[3][16];
#pragma unroll
  for (int gi = 0; gi < 3; ++gi) {
    const int row = gi * Hh + j0 + jj;
    const float4* ph = (const float4*)(Whh + (size_t)row * Hh + kc * 32);
#pragma unroll
    for (int i = 0; i < 8; ++i) {
      float4 v = ph[i];
      whh[gi][4*i+0] = v.x; whh[gi][4*i+1] = v.y;
      whh[gi][4*i+2] = v.z; whh[gi][4*i+3] = v.w;
    }
    const float4* pi = (const float4*)(Wih + (size_t)row * II + kc * 16);
#pragma unroll
    for (int i = 0; i < 4; ++i) {
      float4 v = pi[i];
      wih[gi][4*i+0] = v.x; wih[gi][4*i+1] = v.y;
      wih[gi][4*i+2] = v.z; wih[gi][4*i+3] = v.w;
    }
  }

  // ---- updater state (threads 0..127: br = tid>>5, j = j0 + (tid&31)) --
  float c_st = 0.0f, k_st = -1.0f;
  float bia0 = 0.f, bia1 = 0.f, bia2 = 0.f;
  if (tid < 128) {
    const int jr = tid & 31;
    bia0 = bias[0 * Hh + j0 + jr];
    bia1 = bias[1 * Hh + j0 + jr];
    bia2 = bias[2 * Hh + j0 + jr];
  }

  bool broken = false;  // bounded-spin escape (never taken when co-resident)

  for (int t = 0; t < Tt; ++t) {
    // ---- stage h(t) (LLC-coherent) and x_t into LDS --------------------
    {
      const int bl = tid >> 7;          // 0..3
      const int kk = tid & 127;
      const float* hb = hbuf + (size_t)(t & 1) * Bb * Hh +
                        (size_t)(b0 + bl) * Hh + kk * 4;
      float4 hv;
      hv.x = __hip_atomic_load(hb + 0, __ATOMIC_RELAXED, __HIP_MEMORY_SCOPE_AGENT);
      hv.y = __hip_atomic_load(hb + 1, __ATOMIC_RELAXED, __HIP_MEMORY_SCOPE_AGENT);
      hv.z = __hip_atomic_load(hb + 2, __ATOMIC_RELAXED, __HIP_MEMORY_SCOPE_AGENT);
      hv.w = __hip_atomic_load(hb + 3, __ATOMIC_RELAXED, __HIP_MEMORY_SCOPE_AGENT);
      *(float4*)(h_tile + bl * Hh + kk * 4) = hv;
      const float* xb = x + ((size_t)(b0 + bl) * Tt + t) * II + kk * 2;
      float2 xv = *(const float2*)xb;
      *(float2*)(x_tile + bl * II + kk * 2) = xv;
    }
    __syncthreads();

    // ---- gemv: 576 FMA/thread, broadcast LDS reads ---------------------
    float acc[3][4];
#pragma unroll
    for (int bl = 0; bl < 4; ++bl) {
      const float4* h4 = (const float4*)(h_tile + bl * Hh) + kc * 8;
      const float4* x4 = (const float4*)(x_tile + bl * II) + kc * 4;
      float a0 = 0.f, a1 = 0.f, a2 = 0.f;
#pragma unroll
      for (int i = 0; i < 8; ++i) {
        float4 hv = h4[i];
        a0 = fmaf(whh[0][4*i+0], hv.x, a0); a0 = fmaf(whh[0][4*i+1], hv.y, a0);
        a0 = fmaf(whh[0][4*i+2], hv.z, a0); a0 = fmaf(whh[0][4*i+3], hv.w, a0);
        a1 = fmaf(whh[1][4*i+0], hv.x, a1); a1 = fmaf(whh[1][4*i+1], hv.y, a1);
        a1 = fmaf(whh[1][4*i+2], hv.z, a1); a1 = fmaf(whh[1][4*i+3], hv.w, a1);
        a2 = fmaf(whh[2][4*i+0], hv.x, a2); a2 = fmaf(whh[2][4*i+1], hv.y, a2);
        a2 = fmaf(whh[2][4*i+2], hv.z, a2); a2 = fmaf(whh[2][4*i+3], hv.w, a2);
      }
#pragma unroll
      for (int i = 0; i < 4; ++i) {
        float4 xv = x4[i];
        a0 = fmaf(wih[0][4*i+0], xv.x, a0); a0 = fmaf(wih[0][4*i+1], xv.y, a0);
        a0 = fmaf(wih[0][4*i+2], xv.z, a0); a0 = fmaf(wih[0][4*i+3], xv.w, a0);
        a1 = fmaf(wih[1][4*i+0], xv.x, a1); a1 = fmaf(wih[1][4*i+1], xv.y, a1);
        a1 = fmaf(wih[1][4*i+2], xv.z, a1); a1 = fmaf(wih[1][4*i+3], xv.w, a1);
        a2 = fmaf(wih[2][4*i+0], xv.x, a2); a2 = fmaf(wih[2][4*i+1], xv.y, a2);
        a2 = fmaf(wih[2][4*i+2], xv.z, a2); a2 = fmaf(wih[2][4*i+3], xv.w, a2);
      }
      acc[0][bl] = a0; acc[1][bl] = a1; acc[2][bl] = a2;
    }
    // combine the two k-halves in-register, then one conflict-free store
#pragma unroll
    for (int gi = 0; gi < 3; ++gi)
#pragma unroll
      for (int bl = 0; bl < 4; ++bl) {
        float v = acc[gi][bl] + __shfl_xor(acc[gi][bl], 32, 64);
        if (half == 0) part2[((gi * 4 + bl) * 8 + w) * 33 + jj] = v;
      }
    __syncthreads();

    // ---- reduce + elementwise + store (threads 0..127) -----------------
    if (tid < 128) {
      const int jr = tid & 31, br = tid >> 5;
      float s0 = bia0, s1 = bia1, s2 = bia2;
#pragma unroll
      for (int ww = 0; ww < 8; ++ww) {
        s0 += part2[((0 * 4 + br) * 8 + ww) * 33 + jr];
        s1 += part2[((1 * 4 + br) * 8 + ww) * 33 + jr];
        s2 += part2[((2 * 4 + br) * 8 + ww) * 33 + jr];
      }
      const float tf = (float)t;
      const float r  = 1.0f / (1.0f + __expf(-s0));
      const float o  = 1.0f / (1.0f + __expf(-s1));
      const float gg = 1.0f - 2.0f / (1.0f + __expf(2.0f * s2));
      const float kn = r * (tf - EPSc) + (1.0f - r) * k_st;
      const float d  = tf - kn;
      const float f  = __expf(PV * __logf((d + EPSc) / (d + 1.0f)));
      const float cn = f * c_st + (1.0f - f) * gg;
      const float hn = o * (1.0f - 2.0f / (1.0f + __expf(2.0f * cn)));
      c_st = cn; k_st = kn;
      const int b = b0 + br, j = j0 + jr;
      out[((size_t)b * Tt + t) * Hh + j] = hn;
      __hip_atomic_store(
          hbuf + (size_t)((t + 1) & 1) * Bb * Hh + (size_t)b * Hh + j, hn,
          __ATOMIC_RELAXED, __HIP_MEMORY_SCOPE_AGENT);
      if (t == Tt - 1) {
        const size_t base = (size_t)Bb * Tt * Hh;
        out[base + 0 * Bb * Hh + (size_t)b * Hh + j] = hn;  // h_f
        out[base + 1 * Bb * Hh + (size_t)b * Hh + j] = cn;  // c_f
        out[base + 2 * Bb * Hh + (size_t)b * Hh + j] = kn;  // k_f
      }
    }

    // ---- 16-peer barrier (skip after last step) ------------------------
    if (t < Tt - 1) {
      __syncthreads();  // drains updater global stores before the signal
      if (tid == 0) {
        __hip_atomic_fetch_add(ctr + g, 1u, __ATOMIC_RELEASE,
                               __HIP_MEMORY_SCOPE_AGENT);
        if (!broken) {
          const unsigned target = (unsigned)NPEER * (unsigned)(t + 1);
          int it = 0;
          while (__hip_atomic_load(ctr + g, __ATOMIC_ACQUIRE,
                                   __HIP_MEMORY_SCOPE_AGENT) < target) {
            __builtin_amdgcn_s_sleep(2);
            if (++it > (1 << 22)) { broken = true; break; }
          }
        }
      }
      __syncthreads();  // all threads see acquire via tid0 + barrier
    }
  }
}

extern "C" void kernel_launch(void* const* d_in, const int* in_sizes, int n_in,
                              void* d_out, int out_size, void* d_ws, size_t ws_size,
                              hipStream_t stream) {
  const float* x    = (const float*)d_in[0];
  const float* Wih  = (const float*)d_in[1];
  const float* Whh  = (const float*)d_in[2];
  const float* bias = (const float*)d_in[3];
  float* out = (float*)d_out;

  float*    hbuf = (float*)d_ws;                                  // 2*64*512 f32
  unsigned* ctr  = (unsigned*)((char*)d_ws + 2 * Bb * Hh * sizeof(float));

  plr_init<<<32, 1024, 0, stream>>>(hbuf, ctr);
  plr_main<<<256, 512, 0, stream>>>(x, Wih, Whh, bias, out, hbuf, ctr);
}

// Round 4
// 19999.194 us; speedup vs baseline: 2.3149x; 2.1784x over previous
//
#include <hip/hip_runtime.h>
#include <stdint.h>
#include <stddef.h>

// PowerLawLayer RNN, MI355X persistent-kernel, R4.
//
// R1: 1024-thr wg => 128-VGPR cap, alloc 64 => full weight spill, 39 ms.
// R2: 512-thr wg => alloc 128, demand ~180 => ~50-reg spill = 27 GB FETCH, 44 ms.
// R3: amdgpu_waves_per_eu(2,2) IGNORED (VGPR stayed 128, same spill bytes).
// R4: shrink demand under the 128 cap instead of fighting the allocator:
//   wg = (16 j's) x (full k=768) x (8 batches); 256 wgs = 32 slices x 8
//   batch groups; group g <-> XCD g (bid&7), 32 peers = 32 CUs of one XCD.
//   Weights/thread: 3 gates x 24 k = 72 floats (was 144). FMAs/thread
//   unchanged: 3 x 24 x 8 = 576 (per-SIMD floor 2304 cyc/step).
//   lane: jj=l&15 (hidden), kl=(l>>4)&3; kc=w*4+kl in [0,32): 16 h-k + 8 x-k.
//   Batches in 2 passes of 4 (12 live accs); 4-lane shfl butterfly (xor 16,
//   xor 32) reduces kl before one masked conflict-free LDS partial store.
//   x(t+1) staged during gemv (double-buffered); out[] store issued after
//   the barrier signal so vmcnt drain doesn't wait on HBM.
//
// Workspace: hbuf[2][64][512] f32 ping-pong + ctr[32] u32 = 262,272 B.

#define Hh   512
#define Tt   1024
#define Bb   64
#define II   256
#define EPSc 0.001f
#define PV   0.2f
#define NPEER 32

__global__ __launch_bounds__(1024) void plr_init(float* hbuf, unsigned* ctr) {
  int idx = blockIdx.x * blockDim.x + threadIdx.x;
  if (idx < Bb * Hh) hbuf[idx] = 0.0f;        // h(0) = 0 in buffer 0
  if (idx < 32) ctr[idx] = 0u;                // barrier counters
}

__global__ __launch_bounds__(512, 3)  // min 3 waves/EU -> ~170 VGPR cap;
void plr_main(                        // demand ~120 -> no spill either way
    const float* __restrict__ x,    // [B, T, I]
    const float* __restrict__ Wih,  // [3H, I]
    const float* __restrict__ Whh,  // [3H, H]
    const float* __restrict__ bias, // [3H]
    float* __restrict__ out,        // [B,T,H] ++ h_f ++ c_f ++ k_f
    float* hbuf,                    // [2][B][H]
    unsigned* ctr)                  // [32]
{
  __shared__ float h_tile[8 * Hh];        // [bl][k]      16 KB
  __shared__ float x_tile[2 * 8 * II];    // [buf][bl][k] 16 KB
  __shared__ float part[3264];            // ((gi*8+bl)*8+w)*17 + jj  12.8 KB

  const int tid = threadIdx.x;
  const int w   = tid >> 6;          // wave 0..7
  const int l   = tid & 63;
  const int jj  = l & 15;            // hidden offset within slice
  const int kl  = (l >> 4) & 3;      // k sub-chunk within wave
  const int kc  = (w << 2) | kl;     // k-chunk 0..31
  const int bid = blockIdx.x;
  const int g   = bid & 7;           // batch group == XCD (round-robin)
  const int s   = bid >> 3;          // hidden slice 0..31
  const int j0  = s * 16;
  const int b0  = g * 8;

  // ---- one-time: weights into registers (72 floats/thread) ------------
  float whh[3][16];
  float wih[3][8];
#pragma unroll
  for (int gi = 0; gi < 3; ++gi) {
    const int row = gi * Hh + j0 + jj;
    const float4* ph = (const float4*)(Whh + (size_t)row * Hh + kc * 16);
#pragma unroll
    for (int i = 0; i < 4; ++i) {
      float4 v = ph[i];
      whh[gi][4*i+0] = v.x; whh[gi][4*i+1] = v.y;
      whh[gi][4*i+2] = v.z; whh[gi][4*i+3] = v.w;
    }
    const float4* pi = (const float4*)(Wih + (size_t)row * II + kc * 8);
#pragma unroll
    for (int i = 0; i < 2; ++i) {
      float4 v = pi[i];
      wih[gi][4*i+0] = v.x; wih[gi][4*i+1] = v.y;
      wih[gi][4*i+2] = v.z; wih[gi][4*i+3] = v.w;
    }
  }

  // ---- updater state (threads 0..127: br = tid>>4, jr = tid&15) -------
  float c_st = 0.0f, k_st = -1.0f;
  float bia0 = 0.f, bia1 = 0.f, bia2 = 0.f;
  if (tid < 128) {
    const int jr = tid & 15;
    bia0 = bias[0 * Hh + j0 + jr];
    bia1 = bias[1 * Hh + j0 + jr];
    bia2 = bias[2 * Hh + j0 + jr];
  }

  // ---- prologue: stage x(0) -------------------------------------------
  {
    const int bl = tid >> 6, k4 = (tid & 63) * 4;
    *(float4*)(x_tile + bl * II + k4) =
        *(const float4*)(x + ((size_t)(b0 + bl) * Tt + 0) * II + k4);
  }

  bool broken = false;  // bounded-spin escape (never taken when co-resident)

  for (int t = 0; t < Tt; ++t) {
    // ---- stage h(t) from LLC (agent atomics; peers may be remote) ------
    {
      const float* hb = hbuf + (size_t)(t & 1) * Bb * Hh + (size_t)b0 * Hh;
#pragma unroll
      for (int i = 0; i < 8; ++i)
        h_tile[i * Hh + tid] = __hip_atomic_load(
            hb + i * Hh + tid, __ATOMIC_RELAXED, __HIP_MEMORY_SCOPE_AGENT);
    }
    __syncthreads();  // (A) h_tile + x_tile ready

    // ---- gemv: 576 FMA/thread in 2 passes of 4 batches -----------------
    const float* xt = x_tile + (t & 1) * 8 * II;
#pragma unroll
    for (int pass = 0; pass < 2; ++pass) {
      float acc[3][4];
#pragma unroll
      for (int b4 = 0; b4 < 4; ++b4) {
        const int bl = pass * 4 + b4;
        const float4* h4 = (const float4*)(h_tile + bl * Hh) + kc * 4;
        const float4* x4 = (const float4*)(xt + bl * II) + kc * 2;
        float a0 = 0.f, a1 = 0.f, a2 = 0.f;
#pragma unroll
        for (int i = 0; i < 4; ++i) {
          float4 hv = h4[i];
          a0 = fmaf(whh[0][4*i+0], hv.x, a0); a0 = fmaf(whh[0][4*i+1], hv.y, a0);
          a0 = fmaf(whh[0][4*i+2], hv.z, a0); a0 = fmaf(whh[0][4*i+3], hv.w, a0);
          a1 = fmaf(whh[1][4*i+0], hv.x, a1); a1 = fmaf(whh[1][4*i+1], hv.y, a1);
          a1 = fmaf(whh[1][4*i+2], hv.z, a1); a1 = fmaf(whh[1][4*i+3], hv.w, a1);
          a2 = fmaf(whh[2][4*i+0], hv.x, a2); a2 = fmaf(whh[2][4*i+1], hv.y, a2);
          a2 = fmaf(whh[2][4*i+2], hv.z, a2); a2 = fmaf(whh[2][4*i+3], hv.w, a2);
        }
#pragma unroll
        for (int i = 0; i < 2; ++i) {
          float4 xv = x4[i];
          a0 = fmaf(wih[0][4*i+0], xv.x, a0); a0 = fmaf(wih[0][4*i+1], xv.y, a0);
          a0 = fmaf(wih[0][4*i+2], xv.z, a0); a0 = fmaf(wih[0][4*i+3], xv.w, a0);
          a1 = fmaf(wih[1][4*i+0], xv.x, a1); a1 = fmaf(wih[1][4*i+1], xv.y, a1);
          a1 = fmaf(wih[1][4*i+2], xv.z, a1); a1 = fmaf(wih[1][4*i+3], xv.w, a1);
          a2 = fmaf(wih[2][4*i+0], xv.x, a2); a2 = fmaf(wih[2][4*i+1], xv.y, a2);
          a2 = fmaf(wih[2][4*i+2], xv.z, a2); a2 = fmaf(wih[2][4*i+3], xv.w, a2);
        }
        acc[0][b4] = a0; acc[1][b4] = a1; acc[2][b4] = a2;
      }
      // reduce the 4 kl sub-chunks in-register, one masked store per combo
#pragma unroll
      for (int gi = 0; gi < 3; ++gi)
#pragma unroll
        for (int b4 = 0; b4 < 4; ++b4) {
          float v = acc[gi][b4];
          v += __shfl_xor(v, 16, 64);
          v += __shfl_xor(v, 32, 64);
          if (l < 16)
            part[((gi * 8 + pass * 4 + b4) * 8 + w) * 17 + jj] = v;
        }
    }

    // ---- stage x(t+1) during the gap (independent of h exchange) -------
    if (t + 1 < Tt) {
      const int bl = tid >> 6, k4 = (tid & 63) * 4;
      *(float4*)(x_tile + ((t + 1) & 1) * 8 * II + bl * II + k4) =
          *(const float4*)(x + ((size_t)(b0 + bl) * Tt + (t + 1)) * II + k4);
    }
    __syncthreads();  // (B) partials visible

    // ---- reduce + elementwise + h store (threads 0..127) ---------------
    float hn = 0.f, cn = 0.f, kn = 0.f;
    if (tid < 128) {
      const int jr = tid & 15, br = tid >> 4;
      float s0 = bia0, s1 = bia1, s2 = bia2;
#pragma unroll
      for (int ww = 0; ww < 8; ++ww) {
        s0 += part[((0 * 8 + br) * 8 + ww) * 17 + jr];
        s1 += part[((1 * 8 + br) * 8 + ww) * 17 + jr];
        s2 += part[((2 * 8 + br) * 8 + ww) * 17 + jr];
      }
      const float tf = (float)t;
      const float r  = 1.0f / (1.0f + __expf(-s0));
      const float o  = 1.0f / (1.0f + __expf(-s1));
      const float gg = 1.0f - 2.0f / (1.0f + __expf(2.0f * s2));
      kn = r * (tf - EPSc) + (1.0f - r) * k_st;
      const float d  = tf - kn;
      const float f  = __expf(PV * __logf((d + EPSc) / (d + 1.0f)));
      cn = f * c_st + (1.0f - f) * gg;
      hn = o * (1.0f - 2.0f / (1.0f + __expf(2.0f * cn)));
      c_st = cn; k_st = kn;
      __hip_atomic_store(
          hbuf + (size_t)((t + 1) & 1) * Bb * Hh + (size_t)(b0 + br) * Hh +
              j0 + jr,
          hn, __ATOMIC_RELAXED, __HIP_MEMORY_SCOPE_AGENT);
    }
    __syncthreads();  // (C) drains hbuf atomic stores before the signal

    // ---- signal, then out[] store (off the vmcnt-drain critical path) --
    if (t < Tt - 1 && tid == 0)
      __hip_atomic_fetch_add(ctr + g, 1u, __ATOMIC_RELEASE,
                             __HIP_MEMORY_SCOPE_AGENT);
    if (tid < 128) {
      const int jr = tid & 15, br = tid >> 4;
      const int b = b0 + br, j = j0 + jr;
      out[((size_t)b * Tt + t) * Hh + j] = hn;
      if (t == Tt - 1) {
        const size_t base = (size_t)Bb * Tt * Hh;
        out[base + 0 * Bb * Hh + (size_t)b * Hh + j] = hn;  // h_f
        out[base + 1 * Bb * Hh + (size_t)b * Hh + j] = cn;  // c_f
        out[base + 2 * Bb * Hh + (size_t)b * Hh + j] = kn;  // k_f
      }
    }

    // ---- 32-peer barrier wait ------------------------------------------
    if (t < Tt - 1) {
      if (tid == 0 && !broken) {
        const unsigned target = (unsigned)NPEER * (unsigned)(t + 1);
        int it = 0;
        while (__hip_atomic_load(ctr + g, __ATOMIC_ACQUIRE,
                                 __HIP_MEMORY_SCOPE_AGENT) < target) {
          __builtin_amdgcn_s_sleep(2);
          if (++it > (1 << 22)) { broken = true; break; }
        }
      }
      __syncthreads();  // (D) all threads see the acquire via tid0
    }
  }
}

extern "C" void kernel_launch(void* const* d_in, const int* in_sizes, int n_in,
                              void* d_out, int out_size, void* d_ws, size_t ws_size,
                              hipStream_t stream) {
  const float* x    = (const float*)d_in[0];
  const float* Wih  = (const float*)d_in[1];
  const float* Whh  = (const float*)d_in[2];
  const float* bias = (const float*)d_in[3];
  float* out = (float*)d_out;

  float*    hbuf = (float*)d_ws;                                  // 2*64*512 f32
  unsigned* ctr  = (unsigned*)((char*)d_ws + 2 * Bb * Hh * sizeof(float));

  plr_init<<<32, 1024, 0, stream>>>(hbuf, ctr);
  plr_main<<<256, 512, 0, stream>>>(x, Wih, Whh, bias, out, hbuf, ctr);
}